// Round 6
// baseline (76.209 us; speedup 1.0000x reference)
//
#include <hip/hip_runtime.h>
#include <cmath>

#define B_  16
#define S_  512
#define DI  64
#define DS  64
#define RR  4
#define CH  8      // chunks
#define CL  64     // chunk length
#define CLIPM 1.0e6f

typedef float f32x4 __attribute__((ext_vector_type(4)));

// ws layout (floats):
#define WS_U    524288        // u    [B*S][DI]
#define WS_BM   1048576       // bm   [B*S][DS]
#define WS_CML  1572864       // cml  [B][DS]
#define WS_HIN  1573888       // h_in [B][CH][DI][DS]   (2 MB)
// total 2,098,176 floats ~= 8.4 MB (same footprint as the passing round-3)

// Chunk summaries: f32x4 per chain, [B][CH][DI][DS], at out+1024 (8 MB).
// Written by kA, read by kB (kernel-boundary ordered), overwritten by kC.

__device__ __forceinline__ float clampM(float v) {
    return fminf(fmaxf(v, -CLIPM), CLIPM);
}

__global__ __launch_bounds__(64)
void ssm_k1(const float* __restrict__ x, const float* __restrict__ Wx,
            const float* __restrict__ bx, const float* __restrict__ Wdt,
            const float* __restrict__ bdt, const float* __restrict__ A_log,
            float* __restrict__ ws)
{
    __shared__ float xs[DI];
    __shared__ float dtr_s[RR];
    const int bt   = blockIdx.x;      // b*S + t
    const int lane = threadIdx.x;     // 0..63

    const float xv = x[bt * DI + lane];
    xs[lane] = xv;
    const float a_l = -expf(A_log[lane]);  // row 0 of A_log (rows identical)
    __syncthreads();

    // Bm column (proj col = lane)
    float accB = bx[lane];
    {
        const float* wr = Wx + lane * DI;
        #pragma unroll
        for (int i = 0; i < DI; i += 4) {
            f32x4 w = *reinterpret_cast<const f32x4*>(wr + i);
            accB += w.x * xs[i] + w.y * xs[i + 1] + w.z * xs[i + 2] + w.w * xs[i + 3];
        }
    }
    // dtr (proj cols DS..DS+3), lanes 0..3
    if (lane < RR) {
        float acc = bx[DS + lane];
        const float* wr = Wx + (DS + lane) * DI;
        #pragma unroll
        for (int i = 0; i < DI; i += 4) {
            f32x4 w = *reinterpret_cast<const f32x4*>(wr + i);
            acc += w.x * xs[i] + w.y * xs[i + 1] + w.z * xs[i + 2] + w.w * xs[i + 3];
        }
        dtr_s[lane] = acc;
    }
    __syncthreads();

    // dt for d = lane
    float dtv = bdt[lane];
    #pragma unroll
    for (int r = 0; r < RR; ++r) dtv += dtr_s[r] * Wdt[lane * RR + r];

    // s = sum_d a[d]*dt[d],  asq = |a|^2  (64-lane butterfly)
    float sv = a_l * dtv;
    float qv = a_l * a_l;
    #pragma unroll
    for (int off = 32; off > 0; off >>= 1) {
        sv += __shfl_xor(sv, off);
        qv += __shfl_xor(qv, off);
    }

    const float E   = expm1f(sv);
    const float phi = (fabsf(sv) < 1e-3f)
                        ? fmaf(sv, fmaf(sv, 1.0f / 6.0f, 0.5f), 1.0f)
                        : (E / sv);

    ws[bt * DI + lane]          = phi * dtv;           // phidt
    ws[WS_U + bt * DI + lane]   = xv * (E / qv) * a_l; // u
    ws[WS_BM + bt * DI + lane]  = accB;                // bm

    if ((bt & (S_ - 1)) == (S_ - 1)) {
        float accC = bx[DS + RR + lane];
        const float* wr = Wx + (DS + RR + lane) * DI;
        #pragma unroll
        for (int i = 0; i < DI; i += 4) {
            f32x4 w = *reinterpret_cast<const f32x4*>(wr + i);
            accC += w.x * xs[i] + w.y * xs[i + 1] + w.z * xs[i + 2] + w.w * xs[i + 3];
        }
        ws[WS_CML + (bt >> 9) * DS + lane] = accC;   // bt>>9 == b
    }
}

// Thread mapping for kA/kC: tid -> d = dg*16 + (tid>>4), n0 = (tid&15)*4.
// Each thread owns 4 chains (n = n0..n0+3); wave stores are contiguous.
// blockIdx = ((b*4 + dg)*8 + c), grid 512.

// kA: EXACT chunk summary h -> clamp(alpha*h + beta, lo, hi), 4 chains/thread.
// Summary f32x4 (alpha,beta,lo,hi) at index ((b*CH+c)*DI+d)*DS + n.
__global__ __launch_bounds__(256)
void ssm_kA(const float* __restrict__ ws, const float* __restrict__ A_log,
            float* __restrict__ out)
{
    const int tid = threadIdx.x;
    const int c   = blockIdx.x & 7;
    const int dg  = (blockIdx.x >> 3) & 3;
    const int b   = blockIdx.x >> 5;
    const int dl  = tid >> 4;
    const int n0  = (tid & 15) << 2;
    const int d   = dg * 16 + dl;

    const f32x4 alog4 = *reinterpret_cast<const f32x4*>(A_log + n0);
    float an[4]  = { -expf(alog4.x), -expf(alog4.y), -expf(alog4.z), -expf(alog4.w) };
    float dlt[4];
    #pragma unroll
    for (int k = 0; k < 4; ++k) dlt[k] = (d == n0 + k) ? 1.0f : 0.0f;

    const float* phidt = ws + (size_t)(b * S_) * DI + d;
    const float* uws   = ws + WS_U  + (size_t)(b * S_) * DI + d;
    const float* bmp   = ws + WS_BM + (size_t)(b * S_) * DI + n0;

    float al[4], be[4], lo[4], hi[4];
    #pragma unroll
    for (int k = 0; k < 4; ++k) { al[k] = 1.0f; be[k] = 0.0f; lo[k] = -CLIPM; hi[k] = CLIPM; }

    const int t0 = c * CL;
    #pragma unroll 8
    for (int j = 0; j < CL; ++j) {
        const int t = t0 + j;
        const float pv = phidt[(size_t)t * DI];
        const float uv = uws[(size_t)t * DI];
        const f32x4 bv = *reinterpret_cast<const f32x4*>(bmp + (size_t)t * DI);
        const float bva[4] = { bv.x, bv.y, bv.z, bv.w };
        #pragma unroll
        for (int k = 0; k < 4; ++k) {
            const float av = fmaf(pv, an[k], dlt[k]);
            const float w  = uv * bva[k];
            al[k] = al[k] * av;
            be[k] = fmaf(av, be[k], w);
            const float u1 = fmaf(av, lo[k], w);
            const float u2 = fmaf(av, hi[k], w);
            lo[k] = clampM(fminf(u1, u2));
            hi[k] = clampM(fmaxf(u1, u2));
        }
    }

    f32x4* sum = reinterpret_cast<f32x4*>(out + 1024);
    const size_t sb = (((size_t)b * CH + c) * DI + d) * DS + n0;
    #pragma unroll
    for (int k = 0; k < 4; ++k) {
        f32x4 s = { al[k], be[k], lo[k], hi[k] };
        sum[sb + k] = s;
    }
}

// kB: sequential compose of the 8 chunk summaries (exact); writes h_in to ws.
// grid 64 blocks x 256 threads; blockIdx = b*4 + dg.
__global__ __launch_bounds__(256)
void ssm_kB(float* __restrict__ ws, const float* __restrict__ out)
{
    const int tid = threadIdx.x;
    const int dg  = blockIdx.x & 3;
    const int b   = blockIdx.x >> 2;
    const int dl  = tid >> 4;
    const int n0  = (tid & 15) << 2;
    const int d   = dg * 16 + dl;

    const f32x4* sum = reinterpret_cast<const f32x4*>(out + 1024);

    float h[4] = { 0.0f, 0.0f, 0.0f, 0.0f };
    #pragma unroll
    for (int c = 0; c < CH; ++c) {
        const size_t base = (((size_t)b * CH + c) * DI + d) * DS + n0;
        f32x4 hv = { h[0], h[1], h[2], h[3] };
        *reinterpret_cast<f32x4*>(ws + WS_HIN + base) = hv;
        #pragma unroll
        for (int k = 0; k < 4; ++k) {
            const f32x4 s = sum[base + k];
            h[k] = fminf(fmaxf(fmaf(s.x, h[k], s.y), s.z), s.w);
        }
    }
}

// kC: replay chunk from exact h_in; contiguous f32x4 nontemporal h stores.
__global__ __launch_bounds__(256)
void ssm_kC(const float* __restrict__ ws, const float* __restrict__ x,
            const float* __restrict__ A_log, const float* __restrict__ Dp,
            float* __restrict__ out)
{
    const int tid = threadIdx.x;
    const int c   = blockIdx.x & 7;
    const int dg  = (blockIdx.x >> 3) & 3;
    const int b   = blockIdx.x >> 5;
    const int dl  = tid >> 4;
    const int n0  = (tid & 15) << 2;
    const int d   = dg * 16 + dl;

    const f32x4 alog4 = *reinterpret_cast<const f32x4*>(A_log + n0);
    float an[4]  = { -expf(alog4.x), -expf(alog4.y), -expf(alog4.z), -expf(alog4.w) };
    float dlt[4];
    #pragma unroll
    for (int k = 0; k < 4; ++k) dlt[k] = (d == n0 + k) ? 1.0f : 0.0f;

    const size_t hbase = (((size_t)b * CH + c) * DI + d) * DS + n0;
    const f32x4 h0 = *reinterpret_cast<const f32x4*>(ws + WS_HIN + hbase);
    float h[4] = { h0.x, h0.y, h0.z, h0.w };

    const float* phidt = ws + (size_t)(b * S_) * DI + d;
    const float* uws   = ws + WS_U  + (size_t)(b * S_) * DI + d;
    const float* bmp   = ws + WS_BM + (size_t)(b * S_) * DI + n0;

    const int t0 = c * CL;
    #pragma unroll 8
    for (int j = 0; j < CL; ++j) {
        const int t = t0 + j;
        const float pv = phidt[(size_t)t * DI];
        const float uv = uws[(size_t)t * DI];
        const f32x4 bv = *reinterpret_cast<const f32x4*>(bmp + (size_t)t * DI);
        const float bva[4] = { bv.x, bv.y, bv.z, bv.w };
        #pragma unroll
        for (int k = 0; k < 4; ++k) {
            const float av = fmaf(pv, an[k], dlt[k]);
            h[k] = clampM(fmaf(av, h[k], uv * bva[k]));
        }
        f32x4 hv = { h[0], h[1], h[2], h[3] };
        float* po = out + 1024 + ((size_t)(b * S_ + t) * DI + d) * DS + n0;
        __builtin_nontemporal_store(hv, reinterpret_cast<f32x4*>(po));
    }

    if (c == CH - 1) {
        // y[-1]: v = sum_n h*Cm ; reduce over the 16 threads sharing d
        const f32x4 cm = *reinterpret_cast<const f32x4*>(ws + WS_CML + b * DS + n0);
        float v = h[0] * cm.x + h[1] * cm.y + h[2] * cm.z + h[3] * cm.w;
        v += __shfl_xor(v, 1);
        v += __shfl_xor(v, 2);
        v += __shfl_xor(v, 4);
        v += __shfl_xor(v, 8);
        if ((tid & 15) == 0) {
            const float xi = x[((b * S_) + S_ - 1) * DI + d];
            out[b * DI + d] = v + Dp[d] * xi;
        }
    }
}

extern "C" void kernel_launch(void* const* d_in, const int* in_sizes, int n_in,
                              void* d_out, int out_size, void* d_ws, size_t ws_size,
                              hipStream_t stream)
{
    const float* x     = (const float*)d_in[0];
    const float* Wx    = (const float*)d_in[1];
    const float* bx    = (const float*)d_in[2];
    const float* Wdt   = (const float*)d_in[3];
    const float* bdt   = (const float*)d_in[4];
    const float* A_log = (const float*)d_in[5];
    const float* Dp    = (const float*)d_in[6];
    float* out = (float*)d_out;
    float* ws  = (float*)d_ws;

    ssm_k1<<<B_ * S_, 64, 0, stream>>>(x, Wx, bx, Wdt, bdt, A_log, ws);
    ssm_kA<<<B_ * 4 * CH, 256, 0, stream>>>(ws, A_log, out);
    ssm_kB<<<B_ * 4, 256, 0, stream>>>(ws, out);
    ssm_kC<<<B_ * 4 * CH, 256, 0, stream>>>(ws, x, A_log, Dp, out);
}

// Round 7
// 61.173 us; speedup vs baseline: 1.2458x; 1.2458x over previous
//
#include <hip/hip_runtime.h>
#include <cmath>

#define B_  16
#define S_  512
#define DI  64
#define DS  64
#define RR  4

typedef float f32x4 __attribute__((ext_vector_type(4)));

// ws layout (floats):
//   phidt : [B*S][DI]   offset 0
//   u     : [B*S][DI]   offset  B*S*DI
//   bm    : [B*S][DS]   offset 2*B*S*DI
//   cml   : [B][DS]     offset 3*B*S*DI
#define WS_U    524288
#define WS_BM   1048576
#define WS_CML  1572864

__global__ __launch_bounds__(64)
void ssm_k1(const float* __restrict__ x, const float* __restrict__ Wx,
            const float* __restrict__ bx, const float* __restrict__ Wdt,
            const float* __restrict__ bdt, const float* __restrict__ A_log,
            float* __restrict__ ws)
{
    __shared__ float xs[DI];
    __shared__ float dtr_s[RR];
    const int bt   = blockIdx.x;      // b*S + t
    const int lane = threadIdx.x;     // 0..63

    const float xv = x[bt * DI + lane];
    xs[lane] = xv;
    const float a_l = -expf(A_log[lane]);  // row 0 of A_log (rows identical)
    __syncthreads();

    // Bm column (proj col = lane)
    float accB = bx[lane];
    {
        const float* wr = Wx + lane * DI;
        #pragma unroll
        for (int i = 0; i < DI; i += 4) {
            f32x4 w = *reinterpret_cast<const f32x4*>(wr + i);
            accB += w.x * xs[i] + w.y * xs[i + 1] + w.z * xs[i + 2] + w.w * xs[i + 3];
        }
    }
    // dtr (proj cols DS..DS+3), lanes 0..3
    if (lane < RR) {
        float acc = bx[DS + lane];
        const float* wr = Wx + (DS + lane) * DI;
        #pragma unroll
        for (int i = 0; i < DI; i += 4) {
            f32x4 w = *reinterpret_cast<const f32x4*>(wr + i);
            acc += w.x * xs[i] + w.y * xs[i + 1] + w.z * xs[i + 2] + w.w * xs[i + 3];
        }
        dtr_s[lane] = acc;
    }
    __syncthreads();

    // dt for d = lane
    float dtv = bdt[lane];
    #pragma unroll
    for (int r = 0; r < RR; ++r) dtv += dtr_s[r] * Wdt[lane * RR + r];

    // s = sum_d a[d]*dt[d],  asq = |a|^2  (64-lane butterfly)
    float sv = a_l * dtv;
    float qv = a_l * a_l;
    #pragma unroll
    for (int off = 32; off > 0; off >>= 1) {
        sv += __shfl_xor(sv, off);
        qv += __shfl_xor(qv, off);
    }

    const float E   = expm1f(sv);
    const float phi = (fabsf(sv) < 1e-3f)
                        ? fmaf(sv, fmaf(sv, 1.0f / 6.0f, 0.5f), 1.0f)
                        : (E / sv);

    ws[bt * DI + lane]          = phi * dtv;           // phidt
    ws[WS_U + bt * DI + lane]   = xv * (E / qv) * a_l; // u
    ws[WS_BM + bt * DI + lane]  = accB;                // bm

    if ((bt & (S_ - 1)) == (S_ - 1)) {
        float accC = bx[DS + RR + lane];
        const float* wr = Wx + (DS + RR + lane) * DI;
        #pragma unroll
        for (int i = 0; i < DI; i += 4) {
            f32x4 w = *reinterpret_cast<const f32x4*>(wr + i);
            accC += w.x * xs[i] + w.y * xs[i + 1] + w.z * xs[i + 2] + w.w * xs[i + 3];
        }
        ws[WS_CML + (bt >> 9) * DS + lane] = accC;   // bt>>9 == b
    }
}

// k2: serial scan, ONE change vs round-1: hand-pipelined 16-step register
// tiles — issue all 48 independent loads for a tile, then run the 16
// dependent FMA+clamp+store steps. Arithmetic identical to round 1.
__global__ __launch_bounds__(256)
void ssm_k2(const float* __restrict__ ws, const float* __restrict__ x,
            const float* __restrict__ A_log, const float* __restrict__ Dp,
            float* __restrict__ out)
{
    const int tid  = threadIdx.x;
    const int n    = tid & 63;
    const int dsub = tid >> 6;
    const int b    = blockIdx.x >> 4;
    const int dg   = blockIdx.x & 15;
    const int d    = dg * 4 + dsub;

    const float a_n   = -expf(A_log[n]);
    const float delta = (d == n) ? 1.0f : 0.0f;

    const float* __restrict__ phidt = ws + (size_t)(b * S_) * DI + d;
    const float* __restrict__ uws   = ws + WS_U + (size_t)(b * S_) * DI + d;
    const float* __restrict__ bmws  = ws + WS_BM + (size_t)(b * S_) * DI + n;
    float* __restrict__ po = out + 1024 + (size_t)(b * S_) * (DI * DS) + d * DS + n;

    float h = 0.0f;
    for (int tb = 0; tb < S_; tb += 16) {
        float pv[16], uv[16], bv[16];
        #pragma unroll
        for (int j = 0; j < 16; ++j) {
            pv[j] = phidt[(size_t)(tb + j) * DI];
            uv[j] = uws[(size_t)(tb + j) * DI];
            bv[j] = bmws[(size_t)(tb + j) * DI];
        }
        #pragma unroll
        for (int j = 0; j < 16; ++j) {
            const float av = fmaf(pv[j], a_n, delta);
            h = fmaf(av, h, uv[j] * bv[j]);
            h = fminf(fmaxf(h, -1.0e6f), 1.0e6f);
            po[(size_t)(tb + j) * (DI * DS)] = h;
        }
    }

    // y[-1]: reduce h*Cm over n (one wave == one (b,d) row)
    const float* cml = ws + WS_CML;
    float v = h * cml[b * DS + n];
    #pragma unroll
    for (int off = 32; off > 0; off >>= 1) v += __shfl_xor(v, off);
    if (n == 0) {
        const float xi = x[((b * S_) + S_ - 1) * DI + d];
        out[b * DI + d] = v + Dp[d] * xi;
    }
}

extern "C" void kernel_launch(void* const* d_in, const int* in_sizes, int n_in,
                              void* d_out, int out_size, void* d_ws, size_t ws_size,
                              hipStream_t stream)
{
    const float* x     = (const float*)d_in[0];
    const float* Wx    = (const float*)d_in[1];
    const float* bx    = (const float*)d_in[2];
    const float* Wdt   = (const float*)d_in[3];
    const float* bdt   = (const float*)d_in[4];
    const float* A_log = (const float*)d_in[5];
    const float* Dp    = (const float*)d_in[6];
    float* out = (float*)d_out;
    float* ws  = (float*)d_ws;

    ssm_k1<<<B_ * S_, 64, 0, stream>>>(x, Wx, bx, Wdt, bdt, A_log, ws);
    ssm_k2<<<B_ * 16, 256, 0, stream>>>(ws, x, A_log, Dp, out);
}

// Round 8
// 60.965 us; speedup vs baseline: 1.2500x; 1.0034x over previous
//
#include <hip/hip_runtime.h>
#include <cmath>

#define B_  16
#define S_  512
#define DI  64
#define DS  64
#define RR  4
#define CLIPM 1.0e6f

typedef float f32x4 __attribute__((ext_vector_type(4)));

// ws layout (floats):
#define WS_U    524288
#define WS_BM   1048576
#define WS_CML  1572864

__global__ __launch_bounds__(64)
void ssm_k1(const float* __restrict__ x, const float* __restrict__ Wx,
            const float* __restrict__ bx, const float* __restrict__ Wdt,
            const float* __restrict__ bdt, const float* __restrict__ A_log,
            float* __restrict__ ws)
{
    __shared__ float xs[DI];
    __shared__ float dtr_s[RR];
    const int bt   = blockIdx.x;      // b*S + t
    const int lane = threadIdx.x;     // 0..63

    const float xv = x[bt * DI + lane];
    xs[lane] = xv;
    const float a_l = -expf(A_log[lane]);  // row 0 of A_log (rows identical)
    __syncthreads();

    // Bm column (proj col = lane)
    float accB = bx[lane];
    {
        const float* wr = Wx + lane * DI;
        #pragma unroll
        for (int i = 0; i < DI; i += 4) {
            f32x4 w = *reinterpret_cast<const f32x4*>(wr + i);
            accB += w.x * xs[i] + w.y * xs[i + 1] + w.z * xs[i + 2] + w.w * xs[i + 3];
        }
    }
    // dtr (proj cols DS..DS+3), lanes 0..3
    if (lane < RR) {
        float acc = bx[DS + lane];
        const float* wr = Wx + (DS + lane) * DI;
        #pragma unroll
        for (int i = 0; i < DI; i += 4) {
            f32x4 w = *reinterpret_cast<const f32x4*>(wr + i);
            acc += w.x * xs[i] + w.y * xs[i + 1] + w.z * xs[i + 2] + w.w * xs[i + 3];
        }
        dtr_s[lane] = acc;
    }
    __syncthreads();

    // dt for d = lane
    float dtv = bdt[lane];
    #pragma unroll
    for (int r = 0; r < RR; ++r) dtv += dtr_s[r] * Wdt[lane * RR + r];

    // s = sum_d a[d]*dt[d],  asq = |a|^2  (64-lane butterfly)
    float sv = a_l * dtv;
    float qv = a_l * a_l;
    #pragma unroll
    for (int off = 32; off > 0; off >>= 1) {
        sv += __shfl_xor(sv, off);
        qv += __shfl_xor(qv, off);
    }

    const float E   = expm1f(sv);
    const float phi = (fabsf(sv) < 1e-3f)
                        ? fmaf(sv, fmaf(sv, 1.0f / 6.0f, 0.5f), 1.0f)
                        : (E / sv);

    ws[bt * DI + lane]          = phi * dtv;           // phidt
    ws[WS_U + bt * DI + lane]   = xv * (E / qv) * a_l; // u
    ws[WS_BM + bt * DI + lane]  = accB;                // bm

    if ((bt & (S_ - 1)) == (S_ - 1)) {
        float accC = bx[DS + RR + lane];
        const float* wr = Wx + (DS + RR + lane) * DI;
        #pragma unroll
        for (int i = 0; i < DI; i += 4) {
            f32x4 w = *reinterpret_cast<const f32x4*>(wr + i);
            accC += w.x * xs[i] + w.y * xs[i + 1] + w.z * xs[i + 2] + w.w * xs[i + 3];
        }
        ws[WS_CML + (bt >> 9) * DS + lane] = accC;   // bt>>9 == b
    }
}

// k2: serial scan with LDS-staged operand streams. Inner loop reads LDS
// (lgkmcnt) only; h-stores are the sole vmcnt ops -> the serial chain never
// waits behind the store backlog. Double-buffered 64-step tiles.
__global__ __launch_bounds__(256)
void ssm_k2(const float* __restrict__ ws, const float* __restrict__ x,
            const float* __restrict__ A_log, const float* __restrict__ Dp,
            float* __restrict__ out)
{
    __shared__ float pd_s[2][64][4];
    __shared__ float ud_s[2][64][4];
    __shared__ float bm_s[2][64][64];

    const int tid = threadIdx.x;
    const int n   = tid & 63;      // lane
    const int wid = tid >> 6;      // 0..3
    const int b   = blockIdx.x >> 4;
    const int dg  = blockIdx.x & 15;
    const int d   = dg * 4 + wid;

    const float a_n   = -expf(A_log[n]);
    const float delta = (d == n) ? 1.0f : 0.0f;

    const float* pg = ws + (size_t)(b * S_) * DI;
    const float* ug = ws + WS_U + (size_t)(b * S_) * DI;
    const float* bg = ws + WS_BM + (size_t)(b * S_) * DI;
    float* __restrict__ po = out + 1024 + (size_t)(b * S_) * (DI * DS) + d * DS + n;

    const int js = tid >> 2;   // 0..63  (stage row for pd/ud)
    const int dc = tid & 3;    // 0..3

    f32x4 rb[4]; float rp, ru;

    // ---- stage tile 0 (through registers, then LDS)
    #pragma unroll
    for (int p = 0; p < 4; ++p)
        rb[p] = *reinterpret_cast<const f32x4*>(bg + (size_t)(p * 256 + tid) * 4);
    rp = pg[(size_t)js * DI + dg * 4 + dc];
    ru = ug[(size_t)js * DI + dg * 4 + dc];
    #pragma unroll
    for (int p = 0; p < 4; ++p)
        *reinterpret_cast<f32x4*>(&bm_s[0][0][0] + (size_t)(p * 256 + tid) * 4) = rb[p];
    pd_s[0][js][dc] = rp;
    ud_s[0][js][dc] = ru;
    __syncthreads();

    float h = 0.0f;
    for (int c = 0; c < 8; ++c) {
        const int buf = c & 1;
        const int t0  = c * 64;
        if (c < 7) {
            const size_t t1 = (size_t)(t0 + 64);
            #pragma unroll
            for (int p = 0; p < 4; ++p)
                rb[p] = *reinterpret_cast<const f32x4*>(bg + t1 * DS + (size_t)(p * 256 + tid) * 4);
            rp = pg[(t1 + js) * DI + dg * 4 + dc];
            ru = ug[(t1 + js) * DI + dg * 4 + dc];
        }
        #pragma unroll 8
        for (int j = 0; j < 64; ++j) {
            const float pv = pd_s[buf][j][wid];
            const float uv = ud_s[buf][j][wid];
            const float bv = bm_s[buf][j][n];
            const float av = fmaf(pv, a_n, delta);
            h = fmaf(av, h, uv * bv);
            h = fminf(fmaxf(h, -CLIPM), CLIPM);
            po[(size_t)(t0 + j) * (DI * DS)] = h;
        }
        __syncthreads();   // all waves done reading buf[c&1] & buf[nb] free
        if (c < 7) {
            const int nb = buf ^ 1;
            #pragma unroll
            for (int p = 0; p < 4; ++p)
                *reinterpret_cast<f32x4*>(&bm_s[nb][0][0] + (size_t)(p * 256 + tid) * 4) = rb[p];
            pd_s[nb][js][dc] = rp;
            ud_s[nb][js][dc] = ru;
        }
        __syncthreads();
    }

    // y[-1]: reduce h*Cm over n (one wave == one (b,d) row)
    const float* cml = ws + WS_CML;
    float v = h * cml[b * DS + n];
    #pragma unroll
    for (int off = 32; off > 0; off >>= 1) v += __shfl_xor(v, off);
    if (n == 0) {
        const float xi = x[((b * S_) + S_ - 1) * DI + d];
        out[b * DI + d] = v + Dp[d] * xi;
    }
}

extern "C" void kernel_launch(void* const* d_in, const int* in_sizes, int n_in,
                              void* d_out, int out_size, void* d_ws, size_t ws_size,
                              hipStream_t stream)
{
    const float* x     = (const float*)d_in[0];
    const float* Wx    = (const float*)d_in[1];
    const float* bx    = (const float*)d_in[2];
    const float* Wdt   = (const float*)d_in[3];
    const float* bdt   = (const float*)d_in[4];
    const float* A_log = (const float*)d_in[5];
    const float* Dp    = (const float*)d_in[6];
    float* out = (float*)d_out;
    float* ws  = (float*)d_ws;

    ssm_k1<<<B_ * S_, 64, 0, stream>>>(x, Wx, bx, Wdt, bdt, A_log, ws);
    ssm_k2<<<B_ * 16, 256, 0, stream>>>(ws, x, A_log, Dp, out);
}